// Round 13
// baseline (508.185 us; speedup 1.0000x reference)
//
#include <hip/hip_runtime.h>
#include <hip/hip_bf16.h>
#include <cstdint>
#include <cstddef>

typedef __bf16 bf16;
typedef __attribute__((ext_vector_type(8))) __bf16 bf16x8;
typedef __attribute__((ext_vector_type(4))) float f32x4;
typedef __attribute__((ext_vector_type(4))) int i32x4;
typedef __attribute__((address_space(3))) const bf16* lds_cp;

#define B_SZ  8192
#define NAGENT 8
#define NA_N  16
#define OBS_DD 2048
#define ACT_DD 128
#define IN_DD 2176
#define H1_D  1024
#define H2_D  1024

#define BM 256
#define BN 256
#define BK 64
#define GRID_M (B_SZ / BM)   // 32
#define GRID_N (1024 / BN)   // 4

__device__ __forceinline__ void gload16(const void* g, void* l) {
    __builtin_amdgcn_global_load_lds(
        (__attribute__((address_space(1))) void*)(g),
        (__attribute__((address_space(3))) void*)(l), 16, 0, 0);
}

// ---------- fused preprocessing: X-convert + out-init + W3 transpose ----------
__global__ void k_prep(const float* __restrict__ obs, const float* __restrict__ act,
                       bf16* __restrict__ xb, const float* __restrict__ b3,
                       float* __restrict__ out, const float* __restrict__ W3,
                       bf16* __restrict__ w3t) {
    const int NX = B_SZ * (IN_DD / 8);          // 2228224
    const int NO = B_SZ * 128 / 4;              // 262144 (float4)
    const int NW3 = NAGENT * NA_N * H2_D;       // 131072
    int idx = blockIdx.x * blockDim.x + threadIdx.x;
    if (idx < NX) {
        const int chunks = IN_DD / 8;
        int b = idx / chunks;
        int c8 = idx - b * chunks;
        const float* src = (c8 < OBS_DD / 8)
            ? (obs + (size_t)b * OBS_DD + c8 * 8)
            : (act + (size_t)b * ACT_DD + (c8 - OBS_DD / 8) * 8);
        float4 v0 = ((const float4*)src)[0];
        float4 v1 = ((const float4*)src)[1];
        bf16x8 o;
        o[0] = (bf16)v0.x; o[1] = (bf16)v0.y; o[2] = (bf16)v0.z; o[3] = (bf16)v0.w;
        o[4] = (bf16)v1.x; o[5] = (bf16)v1.y; o[6] = (bf16)v1.z; o[7] = (bf16)v1.w;
        ((bf16x8*)(xb + (size_t)b * IN_DD))[c8] = o;
    } else if (idx < NX + NO) {
        int i = idx - NX;
        int c = (i & 31) * 4;
        float4 v = make_float4(b3[c], b3[c + 1], b3[c + 2], b3[c + 3]);
        ((float4*)out)[i] = v;
    } else if (idx < NX + NO + NW3) {
        int i = idx - NX - NO;
        int a = i / (NA_N * H2_D);
        int n = (i / H2_D) % NA_N;
        int k = i % H2_D;
        w3t[i] = (bf16)W3[(size_t)a * H2_D * NA_N + (size_t)k * NA_N + n];
    }
}

__global__ void k_transpose_w(const float* __restrict__ src, bf16* __restrict__ dst,
                              int K, int H, int maskStart) {
    __shared__ float tile[32][33];
    int a = blockIdx.z;
    int k0 = blockIdx.x * 32, h0 = blockIdx.y * 32;
    const float* s = src + (size_t)a * K * H;
    bf16* d = dst + (size_t)a * K * H;
    int tx = threadIdx.x, ty = threadIdx.y;
    #pragma unroll
    for (int i = 0; i < 32; i += 8) {
        int k = k0 + ty + i;
        float v = s[(size_t)k * H + h0 + tx];
        if (k >= maskStart) {
            int g = k - maskStart;
            if ((g >> 4) == a) v = 0.f;
        }
        tile[ty + i][tx] = v;
    }
    __syncthreads();
    #pragma unroll
    for (int i = 0; i < 32; i += 8) {
        d[(size_t)(h0 + ty + i) * K + k0 + tx] = (bf16)tile[tx][ty + i];
    }
}

// ---------- 256x256x64 GEMM, r10-verified core, persistent workgroups ----------
// Slots (elems): A: (t&1)*16384 ; B: 32768 + (t&1)*16384. 128 KiB total.
// Per assignment: prologue stage+drain+barrier; K-loop = {G1+G2 reads, stage(t+1),
// lgkm(8)->C1, G3, lgkm(4)->C2, G4, lgkm(4)->C3, vmcnt(0), lgkm(0)->C4, barrier};
// epilogue via swizzled C-LDS; trailing barrier guards LDS reuse by next iter.
#define DSR4(d0, d1, d2, d3, addr, O0, O1, O2, O3)                      \
    asm volatile("ds_read_b128 %0, %4 offset:" #O0 "\n\t"               \
                 "ds_read_b128 %1, %4 offset:" #O1 "\n\t"               \
                 "ds_read_b128 %2, %4 offset:" #O2 "\n\t"               \
                 "ds_read_b128 %3, %4 offset:" #O3                      \
                 : "=&v"(d0), "=&v"(d1), "=&v"(d2), "=&v"(d3)           \
                 : "v"(addr))

#define BC(x) __builtin_bit_cast(bf16x8, x)

template<int FUSE>
__global__ __launch_bounds__(512, 1)
void k_gemm256(const bf16* __restrict__ Ain, size_t aStride, int lda,
               const bf16* __restrict__ Bw, const float* __restrict__ bias,
               bf16* __restrict__ Cout, size_t cStride, int K,
               int aOff, int nwg, int iters,
               const bf16* __restrict__ W3Tp, float* __restrict__ outp) {
    extern __shared__ bf16 lds[];   // 65536 elems = 128 KiB

    const int tid = threadIdx.x;
    const int w = tid >> 6;
    const int l = tid & 63;

    const int wr = (w >> 2) * 128;   // wave rows (2M)
    const int wc = (w & 3) * 64;     // wave cols (4N)
    const int lr = l & 15;
    const int lq = l >> 4;

    // fragment addressing (r3/r6/r10-verified): phys chunk = logical ^ (row & 7)
    const int rowA = (wr + lr) * BK;
    const int rowB = (wc + lr) * BK;
    const int ck0 = ((lq ^ (lr & 7)) * 8);
    const int ck1 = (((4 + lq) ^ (lr & 7)) * 8);

    // staging constants (r3/r10-verified)
    const int sRow = w * 16 + (l >> 3);
    const int sCol = ((l & 7) ^ (l >> 3)) * 8;
    const size_t l8a = (size_t)8 * lda;
    const size_t l8b = (size_t)8 * K;

    const int nkt = K / BK;
    const int q8 = nwg >> 3;

    i32x4 ra0, ra1, ra2, ra3;   // A m0-3 ks0
    i32x4 rb0, rb1, rb2, rb3;   // B ks0
    i32x4 rc0, rc1, rc2, rc3;   // A m4-7 ks0
    i32x4 rd0, rd1, rd2, rd3;   // B ks1
    i32x4 re0, re1, re2, re3;   // A m0-3 ks1
    i32x4 rf0, rf1, rf2, rf3;   // A m4-7 ks1

#define STAGE_A(t1, half) do {                                              \
        const bf16* g_ = ((half) ? pA1 : pA0) + (t1) * BK;                  \
        bf16* d_ = &lds[(((t1) & 1) * 16384) + (half) * 8192 + w * 1024];   \
        gload16(g_, d_);                                                    \
        gload16(g_ + l8a, d_ + 512);                                        \
    } while (0)
#define STAGE_B(t2, half) do {                                              \
        const bf16* g_ = ((half) ? pB1 : pB0) + (t2) * BK;                  \
        bf16* d_ = &lds[32768 + (((t2) & 1) * 16384) + (half) * 8192 + w * 1024]; \
        gload16(g_, d_);                                                    \
        gload16(g_ + l8b, d_ + 512);                                        \
    } while (0)

#define MFMA16(ACC0, A0, A1, A2, A3, B0, B1, B2, B3)                        \
    do {                                                                    \
        acc[ACC0+0][0] = __builtin_amdgcn_mfma_f32_16x16x32_bf16(BC(A0), BC(B0), acc[ACC0+0][0], 0, 0, 0); \
        acc[ACC0+1][0] = __builtin_amdgcn_mfma_f32_16x16x32_bf16(BC(A1), BC(B0), acc[ACC0+1][0], 0, 0, 0); \
        acc[ACC0+2][0] = __builtin_amdgcn_mfma_f32_16x16x32_bf16(BC(A2), BC(B0), acc[ACC0+2][0], 0, 0, 0); \
        acc[ACC0+3][0] = __builtin_amdgcn_mfma_f32_16x16x32_bf16(BC(A3), BC(B0), acc[ACC0+3][0], 0, 0, 0); \
        acc[ACC0+0][1] = __builtin_amdgcn_mfma_f32_16x16x32_bf16(BC(A0), BC(B1), acc[ACC0+0][1], 0, 0, 0); \
        acc[ACC0+1][1] = __builtin_amdgcn_mfma_f32_16x16x32_bf16(BC(A1), BC(B1), acc[ACC0+1][1], 0, 0, 0); \
        acc[ACC0+2][1] = __builtin_amdgcn_mfma_f32_16x16x32_bf16(BC(A2), BC(B1), acc[ACC0+2][1], 0, 0, 0); \
        acc[ACC0+3][1] = __builtin_amdgcn_mfma_f32_16x16x32_bf16(BC(A3), BC(B1), acc[ACC0+3][1], 0, 0, 0); \
        acc[ACC0+0][2] = __builtin_amdgcn_mfma_f32_16x16x32_bf16(BC(A0), BC(B2), acc[ACC0+0][2], 0, 0, 0); \
        acc[ACC0+1][2] = __builtin_amdgcn_mfma_f32_16x16x32_bf16(BC(A1), BC(B2), acc[ACC0+1][2], 0, 0, 0); \
        acc[ACC0+2][2] = __builtin_amdgcn_mfma_f32_16x16x32_bf16(BC(A2), BC(B2), acc[ACC0+2][2], 0, 0, 0); \
        acc[ACC0+3][2] = __builtin_amdgcn_mfma_f32_16x16x32_bf16(BC(A3), BC(B2), acc[ACC0+3][2], 0, 0, 0); \
        acc[ACC0+0][3] = __builtin_amdgcn_mfma_f32_16x16x32_bf16(BC(A0), BC(B3), acc[ACC0+0][3], 0, 0, 0); \
        acc[ACC0+1][3] = __builtin_amdgcn_mfma_f32_16x16x32_bf16(BC(A1), BC(B3), acc[ACC0+1][3], 0, 0, 0); \
        acc[ACC0+2][3] = __builtin_amdgcn_mfma_f32_16x16x32_bf16(BC(A2), BC(B3), acc[ACC0+2][3], 0, 0, 0); \
        acc[ACC0+3][3] = __builtin_amdgcn_mfma_f32_16x16x32_bf16(BC(A3), BC(B3), acc[ACC0+3][3], 0, 0, 0); \
    } while (0)

    for (int it = 0; it < iters; ++it) {
        // assignment id reproduces the r10 XCD-chunked mapping exactly:
        // b&7 invariant per wg (grid % 8 == 0), rounds advance b>>3 by grid/8.
        const int b = blockIdx.x + gridDim.x * it;
        const int lin2 = (b & 7) * q8 + (b >> 3);
        const int mt = lin2 % GRID_M;
        const int rest = lin2 / GRID_M;
        const int ntile = rest % GRID_N;
        const int az = rest / GRID_N;
        const int aw = az + aOff;

        const int rowBase = mt * BM;
        const int colBase = ntile * BN;
        const bf16* Aag = Ain + (size_t)az * aStride;
        const bf16* Bag = Bw + (size_t)aw * (size_t)1024 * K;

        const bf16* pA0 = Aag + (size_t)(rowBase + sRow) * lda + sCol;
        const bf16* pA1 = Aag + (size_t)(rowBase + 128 + sRow) * lda + sCol;
        const bf16* pB0 = Bag + (size_t)(colBase + sRow) * K + sCol;
        const bf16* pB1 = Bag + (size_t)(colBase + 128 + sRow) * K + sCol;

        f32x4 acc[8][4] = {};

        // prologue: stage tile 0, drain, barrier
        STAGE_A(0, 0); STAGE_A(0, 1);
        STAGE_B(0, 0); STAGE_B(0, 1);
        asm volatile("s_waitcnt vmcnt(0)" ::: "memory");
        __builtin_amdgcn_s_barrier();

        for (int t = 0; t < nkt; ++t) {
            const int dbuf = (t & 1) * 16384;
            lds_cp adrA0 = (lds_cp)lds + (dbuf + rowA + ck0);
            lds_cp adrA1 = (lds_cp)lds + (dbuf + rowA + ck1);
            lds_cp adrB0 = (lds_cp)lds + (32768 + dbuf + rowB + ck0);
            lds_cp adrB1 = (lds_cp)lds + (32768 + dbuf + rowB + ck1);

            DSR4(ra0, ra1, ra2, ra3, adrA0, 0, 2048, 4096, 6144);
            DSR4(rb0, rb1, rb2, rb3, adrB0, 0, 2048, 4096, 6144);
            DSR4(rc0, rc1, rc2, rc3, adrA0, 8192, 10240, 12288, 14336);
            DSR4(rd0, rd1, rd2, rd3, adrB1, 0, 2048, 4096, 6144);

            if (t + 1 < nkt) {
                STAGE_A(t + 1, 0); STAGE_A(t + 1, 1);
                STAGE_B(t + 1, 0); STAGE_B(t + 1, 1);
            }

            asm volatile("s_waitcnt lgkmcnt(8)" ::: "memory");   // G1 done
            __builtin_amdgcn_sched_barrier(0);
            __builtin_amdgcn_s_setprio(1);
            MFMA16(0, ra0, ra1, ra2, ra3, rb0, rb1, rb2, rb3);   // m0-3 ks0
            __builtin_amdgcn_s_setprio(0);

            DSR4(re0, re1, re2, re3, adrA1, 0, 2048, 4096, 6144); // G3
            asm volatile("s_waitcnt lgkmcnt(4)" ::: "memory");   // G2 done
            __builtin_amdgcn_sched_barrier(0);
            __builtin_amdgcn_s_setprio(1);
            MFMA16(4, rc0, rc1, rc2, rc3, rb0, rb1, rb2, rb3);   // m4-7 ks0
            __builtin_amdgcn_s_setprio(0);

            DSR4(rf0, rf1, rf2, rf3, adrA1, 8192, 10240, 12288, 14336); // G4
            asm volatile("s_waitcnt lgkmcnt(4)" ::: "memory");   // G3 done
            __builtin_amdgcn_sched_barrier(0);
            __builtin_amdgcn_s_setprio(1);
            MFMA16(0, re0, re1, re2, re3, rd0, rd1, rd2, rd3);   // m0-3 ks1
            __builtin_amdgcn_s_setprio(0);

            asm volatile("s_waitcnt vmcnt(0)" ::: "memory");
            asm volatile("s_waitcnt lgkmcnt(0)" ::: "memory");   // G4 done
            __builtin_amdgcn_sched_barrier(0);
            __builtin_amdgcn_s_setprio(1);
            MFMA16(4, rf0, rf1, rf2, rf3, rd0, rd1, rd2, rd3);   // m4-7 ks1
            __builtin_amdgcn_s_setprio(0);

            __builtin_amdgcn_s_barrier();
        }

        // ---- epilogue: bias + relu -> swizzled C-LDS tile [256][256] bf16
        __syncthreads();
        const float* bAg = bias + (size_t)aw * 1024;
        float bb4[4];
        #pragma unroll
        for (int n = 0; n < 4; ++n) bb4[n] = bAg[colBase + wc + n * 16 + lr];
        #pragma unroll
        for (int m = 0; m < 8; ++m)
            #pragma unroll
            for (int n = 0; n < 4; ++n)
                #pragma unroll
                for (int r = 0; r < 4; ++r) {
                    float v = acc[m][n][r] + bb4[n];
                    v = fmaxf(v, 0.f);
                    int row = wr + m * 16 + lq * 4 + r;
                    int col = wc + n * 16 + lr;
                    lds[row * 256 + ((((col >> 3) ^ (row & 7)) << 3) | (col & 7))] = (bf16)v;
                }
        __syncthreads();

        if constexpr (!FUSE) {
            bf16* Cg = Cout + (size_t)az * cStride + (size_t)rowBase * 1024 + colBase;
            const int er = tid >> 5;
            const int ec = tid & 31;
            #pragma unroll
            for (int i = 0; i < 16; ++i) {
                int row = i * 16 + er;
                int phys = ec ^ (row & 7);
                *(bf16x8*)&Cg[(size_t)row * 1024 + ec * 8] =
                    *(const bf16x8*)&lds[row * 256 + phys * 8];
            }
        } else {
            // fused L3 (r3-verified): h2 tile x W3T[aw] -> atomicAdd into out
            const bf16* w3a = W3Tp + (size_t)aw * NA_N * H2_D;
            f32x4 oacc[2] = {};
            const int frow0 = w * 32;
            #pragma unroll
            for (int ks = 0; ks < 8; ++ks) {
                bf16x8 bfrag = *(const bf16x8*)&w3a[(size_t)lr * H2_D + colBase + ks * 32 + lq * 8];
                #pragma unroll
                for (int mm = 0; mm < 2; ++mm) {
                    int row = frow0 + mm * 16 + lr;
                    int lc = (ks * 4 + lq) ^ (row & 7);
                    bf16x8 afrag = *(const bf16x8*)&lds[row * 256 + lc * 8];
                    oacc[mm] = __builtin_amdgcn_mfma_f32_16x16x32_bf16(afrag, bfrag, oacc[mm], 0, 0, 0);
                }
            }
            #pragma unroll
            for (int mm = 0; mm < 2; ++mm)
                #pragma unroll
                for (int r = 0; r < 4; ++r)
                    atomicAdd(&outp[(size_t)(rowBase + frow0 + mm * 16 + lq * 4 + r) * 128
                                    + aw * NA_N + lr], oacc[mm][r]);
        }

        // guard: all waves done reading C-LDS before next assignment stages into it
        __syncthreads();
    }
#undef STAGE_A
#undef STAGE_B
#undef MFMA16
}

// ---------- launcher ----------
extern "C" void kernel_launch(void* const* d_in, const int* in_sizes, int n_in,
                              void* d_out, int out_size, void* d_ws, size_t ws_size,
                              hipStream_t stream) {
    const float* obs = (const float*)d_in[0];
    const float* act = (const float*)d_in[1];
    const float* W1 = (const float*)d_in[2];
    const float* b1 = (const float*)d_in[3];
    const float* W2 = (const float*)d_in[4];
    const float* b2 = (const float*)d_in[5];
    const float* W3 = (const float*)d_in[6];
    const float* b3 = (const float*)d_in[7];
    float* out = (float*)d_out;

    const size_t SZ_XB  = (size_t)B_SZ * IN_DD * 2;
    const size_t SZ_W1T = (size_t)NAGENT * H1_D * IN_DD * 2;
    const size_t SZ_W2T = (size_t)NAGENT * H1_D * H2_D * 2;
    const size_t SZ_W3T = (size_t)NAGENT * NA_N * H2_D * 2;
    const size_t SZ_H1  = (size_t)B_SZ * H1_D * 2;
    const size_t SZ_FIX = SZ_XB + SZ_W1T + SZ_W2T + SZ_W3T;

    char* ws = (char*)d_ws;
    bf16* Xb  = (bf16*)ws;
    bf16* W1T = (bf16*)(ws + SZ_XB);
    bf16* W2T = (bf16*)(ws + SZ_XB + SZ_W1T);
    bf16* W3T = (bf16*)(ws + SZ_XB + SZ_W1T + SZ_W2T);
    char* hbase = ws + SZ_FIX;

    // largest G (agents per pass) that fits: h1 only (h2/L3 fused)
    int G = 8;
    while (G > 1 && ws_size < SZ_FIX + (size_t)G * SZ_H1) G >>= 1;

    (void)hipFuncSetAttribute((const void*)k_gemm256<0>,
                              hipFuncAttributeMaxDynamicSharedMemorySize, 131072);
    (void)hipFuncSetAttribute((const void*)k_gemm256<1>,
                              hipFuncAttributeMaxDynamicSharedMemorySize, 131072);

    // fused preprocessing: X convert + out=b3 init + W3 transpose
    {
        const int NX = B_SZ * (IN_DD / 8);
        const int NO = B_SZ * 128 / 4;
        const int NW3 = NAGENT * NA_N * H2_D;
        int n = NX + NO + NW3;
        k_prep<<<(n + 255) / 256, 256, 0, stream>>>(obs, act, Xb, b3, out, W3, W3T);
    }
    k_transpose_w<<<dim3(IN_DD / 32, H1_D / 32, NAGENT), dim3(32, 8), 0, stream>>>(
        W1, W1T, IN_DD, H1_D, OBS_DD);
    k_transpose_w<<<dim3(H1_D / 32, H2_D / 32, NAGENT), dim3(32, 8), 0, stream>>>(
        W2, W2T, H1_D, H2_D, 1 << 30);

    const size_t agElems = (size_t)B_SZ * H1_D;
    bf16* h1 = (bf16*)hbase;

    for (int g0 = 0; g0 < NAGENT; g0 += G) {
        const int nwg = 128 * G;
        const int grd = (nwg >= 256) ? 256 : nwg;
        const int iters = nwg / grd;
        k_gemm256<0><<<grd, 512, 131072, stream>>>(
            Xb, 0, IN_DD, W1T, b1, h1, agElems, IN_DD, g0, nwg, iters, nullptr, nullptr);
        k_gemm256<1><<<grd, 512, 131072, stream>>>(
            h1, agElems, H1_D, W2T, b2, nullptr, 0, H1_D, g0, nwg, iters, W3T, out);
    }
    (void)in_sizes; (void)n_in; (void)out_size;
}

// Round 14
// 441.871 us; speedup vs baseline: 1.1501x; 1.1501x over previous
//
#include <hip/hip_runtime.h>
#include <hip/hip_bf16.h>
#include <cstdint>
#include <cstddef>

typedef __bf16 bf16;
typedef __attribute__((ext_vector_type(8))) __bf16 bf16x8;
typedef __attribute__((ext_vector_type(4))) float f32x4;
typedef __attribute__((ext_vector_type(4))) int i32x4;
typedef __attribute__((address_space(3))) const bf16* lds_cp;

#define B_SZ  8192
#define NAGENT 8
#define NA_N  16
#define OBS_DD 2048
#define ACT_DD 128
#define IN_DD 2176
#define H1_D  1024
#define H2_D  1024

#define BM 256
#define BN 256
#define BK 64
#define GRID_M (B_SZ / BM)   // 32
#define GRID_N (1024 / BN)   // 4

__device__ __forceinline__ void gload16(const void* g, void* l) {
    __builtin_amdgcn_global_load_lds(
        (__attribute__((address_space(1))) void*)(g),
        (__attribute__((address_space(3))) void*)(l), 16, 0, 0);
}

// ---------- fused preprocessing: X-convert + out-init + W3 transpose (r13-verified) ----------
__global__ void k_prep(const float* __restrict__ obs, const float* __restrict__ act,
                       bf16* __restrict__ xb, const float* __restrict__ b3,
                       float* __restrict__ out, const float* __restrict__ W3,
                       bf16* __restrict__ w3t) {
    const int NX = B_SZ * (IN_DD / 8);          // 2228224
    const int NO = B_SZ * 128 / 4;              // 262144 (float4)
    const int NW3 = NAGENT * NA_N * H2_D;       // 131072
    int idx = blockIdx.x * blockDim.x + threadIdx.x;
    if (idx < NX) {
        const int chunks = IN_DD / 8;
        int b = idx / chunks;
        int c8 = idx - b * chunks;
        const float* src = (c8 < OBS_DD / 8)
            ? (obs + (size_t)b * OBS_DD + c8 * 8)
            : (act + (size_t)b * ACT_DD + (c8 - OBS_DD / 8) * 8);
        float4 v0 = ((const float4*)src)[0];
        float4 v1 = ((const float4*)src)[1];
        bf16x8 o;
        o[0] = (bf16)v0.x; o[1] = (bf16)v0.y; o[2] = (bf16)v0.z; o[3] = (bf16)v0.w;
        o[4] = (bf16)v1.x; o[5] = (bf16)v1.y; o[6] = (bf16)v1.z; o[7] = (bf16)v1.w;
        ((bf16x8*)(xb + (size_t)b * IN_DD))[c8] = o;
    } else if (idx < NX + NO) {
        int i = idx - NX;
        int c = (i & 31) * 4;
        float4 v = make_float4(b3[c], b3[c + 1], b3[c + 2], b3[c + 3]);
        ((float4*)out)[i] = v;
    } else if (idx < NX + NO + NW3) {
        int i = idx - NX - NO;
        int a = i / (NA_N * H2_D);
        int n = (i / H2_D) % NA_N;
        int k = i % H2_D;
        w3t[i] = (bf16)W3[(size_t)a * H2_D * NAGENT * 0 + (size_t)a * H2_D * NA_N + (size_t)k * NA_N + n];
    }
}

// merged W1+W2 transpose: z<8 -> W1 (K=IN_DD, masked), z>=8 -> W2 (K=H1_D)
__global__ void k_transpose_w12(const float* __restrict__ W1, bf16* __restrict__ W1T,
                                const float* __restrict__ W2, bf16* __restrict__ W2T) {
    __shared__ float tile[32][33];
    const int z = blockIdx.z;
    const bool isW1 = (z < 8);
    const int a = isW1 ? z : z - 8;
    const int K = isW1 ? IN_DD : H1_D;
    const int H = 1024;
    const int maskStart = isW1 ? OBS_DD : (1 << 30);
    if (!isW1 && blockIdx.x >= (H1_D / 32)) return;   // block-uniform, safe
    const float* s = (isW1 ? W1 : W2) + (size_t)a * K * H;
    bf16* d = (isW1 ? W1T : W2T) + (size_t)a * K * H;
    int k0 = blockIdx.x * 32, h0 = blockIdx.y * 32;
    int tx = threadIdx.x, ty = threadIdx.y;
    #pragma unroll
    for (int i = 0; i < 32; i += 8) {
        int k = k0 + ty + i;
        float v = s[(size_t)k * H + h0 + tx];
        if (k >= maskStart) {
            int g = k - maskStart;
            if ((g >> 4) == a) v = 0.f;
        }
        tile[ty + i][tx] = v;
    }
    __syncthreads();
    #pragma unroll
    for (int i = 0; i < 32; i += 8) {
        d[(size_t)(h0 + ty + i) * K + k0 + tx] = (bf16)tile[tx][ty + i];
    }
}

// ---------- 256x256x64 GEMM: r10-verified core (1 barrier/K-tile, counted lgkm) ----------
// Slots (elems): A: (t&1)*16384 ; B: 32768 + (t&1)*16384. 128 KiB total.
#define DSR4(d0, d1, d2, d3, addr, O0, O1, O2, O3)                      \
    asm volatile("ds_read_b128 %0, %4 offset:" #O0 "\n\t"               \
                 "ds_read_b128 %1, %4 offset:" #O1 "\n\t"               \
                 "ds_read_b128 %2, %4 offset:" #O2 "\n\t"               \
                 "ds_read_b128 %3, %4 offset:" #O3                      \
                 : "=&v"(d0), "=&v"(d1), "=&v"(d2), "=&v"(d3)           \
                 : "v"(addr))

#define BC(x) __builtin_bit_cast(bf16x8, x)

template<int FUSE>
__global__ __launch_bounds__(512, 1)
void k_gemm256(const bf16* __restrict__ Ain, size_t aStride, int lda,
               const bf16* __restrict__ Bw, const float* __restrict__ bias,
               bf16* __restrict__ Cout, size_t cStride, int K,
               int aOff, int gridZ,
               const bf16* __restrict__ W3Tp, float* __restrict__ outp) {
    extern __shared__ bf16 lds[];   // 65536 elems = 128 KiB

    const int tid = threadIdx.x;
    const int w = tid >> 6;
    const int l = tid & 63;

    // XCD-chunked remap (nwg = 128*gridZ, % 8 == 0)
    int flat = blockIdx.x + GRID_M * (blockIdx.y + GRID_N * blockIdx.z);
    int q8 = (GRID_M * GRID_N * gridZ) >> 3;
    int lin2 = (flat & 7) * q8 + (flat >> 3);
    const int mt = lin2 % GRID_M;
    int rest = lin2 / GRID_M;
    const int ntile = rest % GRID_N;
    const int az = rest / GRID_N;
    const int aw = az + aOff;

    const int rowBase = mt * BM;
    const int colBase = ntile * BN;
    const bf16* Aag = Ain + (size_t)az * aStride;
    const bf16* Bag = Bw + (size_t)aw * (size_t)1024 * K;

    const int wr = (w >> 2) * 128;   // wave rows (2M)
    const int wc = (w & 3) * 64;     // wave cols (4N)
    const int lr = l & 15;
    const int lq = l >> 4;

    // fragment addressing (r3/r6/r10-verified): phys chunk = logical ^ (row & 7)
    const int rowA = (wr + lr) * BK;
    const int rowB = (wc + lr) * BK;
    const int ck0 = ((lq ^ (lr & 7)) * 8);
    const int ck1 = (((4 + lq) ^ (lr & 7)) * 8);

    // staging (r3/r10-verified): lane -> row w*16+(l>>3), pre-swizzled col
    const int sRow = w * 16 + (l >> 3);
    const int sCol = ((l & 7) ^ (l >> 3)) * 8;
    const bf16* pA0 = Aag + (size_t)(rowBase + sRow) * lda + sCol;
    const bf16* pA1 = Aag + (size_t)(rowBase + 128 + sRow) * lda + sCol;
    const bf16* pB0 = Bag + (size_t)(colBase + sRow) * K + sCol;
    const bf16* pB1 = Bag + (size_t)(colBase + 128 + sRow) * K + sCol;
    const size_t l8a = (size_t)8 * lda;
    const size_t l8b = (size_t)8 * K;

    const int nkt = K / BK;

#define STAGE_A(t1, half) do {                                              \
        const bf16* g_ = ((half) ? pA1 : pA0) + (t1) * BK;                  \
        bf16* d_ = &lds[(((t1) & 1) * 16384) + (half) * 8192 + w * 1024];   \
        gload16(g_, d_);                                                    \
        gload16(g_ + l8a, d_ + 512);                                        \
    } while (0)
#define STAGE_B(t2, half) do {                                              \
        const bf16* g_ = ((half) ? pB1 : pB0) + (t2) * BK;                  \
        bf16* d_ = &lds[32768 + (((t2) & 1) * 16384) + (half) * 8192 + w * 1024]; \
        gload16(g_, d_);                                                    \
        gload16(g_ + l8b, d_ + 512);                                        \
    } while (0)

    f32x4 acc[8][4] = {};
    i32x4 ra0, ra1, ra2, ra3;   // A m0-3 ks0
    i32x4 rb0, rb1, rb2, rb3;   // B ks0
    i32x4 rc0, rc1, rc2, rc3;   // A m4-7 ks0
    i32x4 rd0, rd1, rd2, rd3;   // B ks1
    i32x4 re0, re1, re2, re3;   // A m0-3 ks1
    i32x4 rf0, rf1, rf2, rf3;   // A m4-7 ks1

#define MFMA16(ACC0, A0, A1, A2, A3, B0, B1, B2, B3)                        \
    do {                                                                    \
        acc[ACC0+0][0] = __builtin_amdgcn_mfma_f32_16x16x32_bf16(BC(A0), BC(B0), acc[ACC0+0][0], 0, 0, 0); \
        acc[ACC0+1][0] = __builtin_amdgcn_mfma_f32_16x16x32_bf16(BC(A1), BC(B0), acc[ACC0+1][0], 0, 0, 0); \
        acc[ACC0+2][0] = __builtin_amdgcn_mfma_f32_16x16x32_bf16(BC(A2), BC(B0), acc[ACC0+2][0], 0, 0, 0); \
        acc[ACC0+3][0] = __builtin_amdgcn_mfma_f32_16x16x32_bf16(BC(A3), BC(B0), acc[ACC0+3][0], 0, 0, 0); \
        acc[ACC0+0][1] = __builtin_amdgcn_mfma_f32_16x16x32_bf16(BC(A0), BC(B1), acc[ACC0+0][1], 0, 0, 0); \
        acc[ACC0+1][1] = __builtin_amdgcn_mfma_f32_16x16x32_bf16(BC(A1), BC(B1), acc[ACC0+1][1], 0, 0, 0); \
        acc[ACC0+2][1] = __builtin_amdgcn_mfma_f32_16x16x32_bf16(BC(A2), BC(B1), acc[ACC0+2][1], 0, 0, 0); \
        acc[ACC0+3][1] = __builtin_amdgcn_mfma_f32_16x16x32_bf16(BC(A3), BC(B1), acc[ACC0+3][1], 0, 0, 0); \
        acc[ACC0+0][2] = __builtin_amdgcn_mfma_f32_16x16x32_bf16(BC(A0), BC(B2), acc[ACC0+0][2], 0, 0, 0); \
        acc[ACC0+1][2] = __builtin_amdgcn_mfma_f32_16x16x32_bf16(BC(A1), BC(B2), acc[ACC0+1][2], 0, 0, 0); \
        acc[ACC0+2][2] = __builtin_amdgcn_mfma_f32_16x16x32_bf16(BC(A2), BC(B2), acc[ACC0+2][2], 0, 0, 0); \
        acc[ACC0+3][2] = __builtin_amdgcn_mfma_f32_16x16x32_bf16(BC(A3), BC(B2), acc[ACC0+3][2], 0, 0, 0); \
        acc[ACC0+0][3] = __builtin_amdgcn_mfma_f32_16x16x32_bf16(BC(A0), BC(B3), acc[ACC0+0][3], 0, 0, 0); \
        acc[ACC0+1][3] = __builtin_amdgcn_mfma_f32_16x16x32_bf16(BC(A1), BC(B3), acc[ACC0+1][3], 0, 0, 0); \
        acc[ACC0+2][3] = __builtin_amdgcn_mfma_f32_16x16x32_bf16(BC(A2), BC(B3), acc[ACC0+2][3], 0, 0, 0); \
        acc[ACC0+3][3] = __builtin_amdgcn_mfma_f32_16x16x32_bf16(BC(A3), BC(B3), acc[ACC0+3][3], 0, 0, 0); \
    } while (0)

    // prologue: stage tile 0, drain, barrier
    STAGE_A(0, 0); STAGE_A(0, 1);
    STAGE_B(0, 0); STAGE_B(0, 1);
    asm volatile("s_waitcnt vmcnt(0)" ::: "memory");
    __builtin_amdgcn_s_barrier();

    for (int t = 0; t < nkt; ++t) {
        const int dbuf = (t & 1) * 16384;
        lds_cp adrA0 = (lds_cp)lds + (dbuf + rowA + ck0);
        lds_cp adrA1 = (lds_cp)lds + (dbuf + rowA + ck1);
        lds_cp adrB0 = (lds_cp)lds + (32768 + dbuf + rowB + ck0);
        lds_cp adrB1 = (lds_cp)lds + (32768 + dbuf + rowB + ck1);

        DSR4(ra0, ra1, ra2, ra3, adrA0, 0, 2048, 4096, 6144);
        DSR4(rb0, rb1, rb2, rb3, adrB0, 0, 2048, 4096, 6144);
        DSR4(rc0, rc1, rc2, rc3, adrA0, 8192, 10240, 12288, 14336);
        DSR4(rd0, rd1, rd2, rd3, adrB1, 0, 2048, 4096, 6144);

        if (t + 1 < nkt) {
            STAGE_A(t + 1, 0); STAGE_A(t + 1, 1);
            STAGE_B(t + 1, 0); STAGE_B(t + 1, 1);
        }

        asm volatile("s_waitcnt lgkmcnt(8)" ::: "memory");   // G1 done
        __builtin_amdgcn_sched_barrier(0);
        __builtin_amdgcn_s_setprio(1);
        MFMA16(0, ra0, ra1, ra2, ra3, rb0, rb1, rb2, rb3);   // m0-3 ks0
        __builtin_amdgcn_s_setprio(0);

        DSR4(re0, re1, re2, re3, adrA1, 0, 2048, 4096, 6144); // G3
        asm volatile("s_waitcnt lgkmcnt(4)" ::: "memory");   // G2 done
        __builtin_amdgcn_sched_barrier(0);
        __builtin_amdgcn_s_setprio(1);
        MFMA16(4, rc0, rc1, rc2, rc3, rb0, rb1, rb2, rb3);   // m4-7 ks0
        __builtin_amdgcn_s_setprio(0);

        DSR4(rf0, rf1, rf2, rf3, adrA1, 8192, 10240, 12288, 14336); // G4
        asm volatile("s_waitcnt lgkmcnt(4)" ::: "memory");   // G3 done
        __builtin_amdgcn_sched_barrier(0);
        __builtin_amdgcn_s_setprio(1);
        MFMA16(0, re0, re1, re2, re3, rd0, rd1, rd2, rd3);   // m0-3 ks1
        __builtin_amdgcn_s_setprio(0);

        asm volatile("s_waitcnt vmcnt(0)" ::: "memory");
        asm volatile("s_waitcnt lgkmcnt(0)" ::: "memory");   // G4 done
        __builtin_amdgcn_sched_barrier(0);
        __builtin_amdgcn_s_setprio(1);
        MFMA16(4, rf0, rf1, rf2, rf3, rd0, rd1, rd2, rd3);   // m4-7 ks1
        __builtin_amdgcn_s_setprio(0);

        __builtin_amdgcn_s_barrier();
    }
#undef STAGE_A
#undef STAGE_B
#undef MFMA16

    // ---- epilogue: bias + relu -> swizzled C-LDS tile [256][256] bf16 (r3-verified)
    __syncthreads();
    const float* bAg = bias + (size_t)aw * 1024;
    float bb4[4];
    #pragma unroll
    for (int n = 0; n < 4; ++n) bb4[n] = bAg[colBase + wc + n * 16 + lr];
    #pragma unroll
    for (int m = 0; m < 8; ++m)
        #pragma unroll
        for (int n = 0; n < 4; ++n)
            #pragma unroll
            for (int r = 0; r < 4; ++r) {
                float v = acc[m][n][r] + bb4[n];
                v = fmaxf(v, 0.f);
                int row = wr + m * 16 + lq * 4 + r;
                int col = wc + n * 16 + lr;
                lds[row * 256 + ((((col >> 3) ^ (row & 7)) << 3) | (col & 7))] = (bf16)v;
            }
    __syncthreads();

    if constexpr (!FUSE) {
        bf16* Cg = Cout + (size_t)az * cStride + (size_t)rowBase * 1024 + colBase;
        const int er = tid >> 5;
        const int ec = tid & 31;
        #pragma unroll
        for (int i = 0; i < 16; ++i) {
            int row = i * 16 + er;
            int phys = ec ^ (row & 7);
            *(bf16x8*)&Cg[(size_t)row * 1024 + ec * 8] =
                *(const bf16x8*)&lds[row * 256 + phys * 8];
        }
    } else {
        // fused L3 (r3-verified): h2 tile x W3T[aw] -> atomicAdd into out
        const bf16* w3a = W3Tp + (size_t)aw * NA_N * H2_D;
        f32x4 oacc[2] = {};
        const int frow0 = w * 32;
        #pragma unroll
        for (int ks = 0; ks < 8; ++ks) {
            bf16x8 bfrag = *(const bf16x8*)&w3a[(size_t)lr * H2_D + colBase + ks * 32 + lq * 8];
            #pragma unroll
            for (int mm = 0; mm < 2; ++mm) {
                int row = frow0 + mm * 16 + lr;
                int lc = (ks * 4 + lq) ^ (row & 7);
                bf16x8 afrag = *(const bf16x8*)&lds[row * 256 + lc * 8];
                oacc[mm] = __builtin_amdgcn_mfma_f32_16x16x32_bf16(afrag, bfrag, oacc[mm], 0, 0, 0);
            }
        }
        #pragma unroll
        for (int mm = 0; mm < 2; ++mm)
            #pragma unroll
            for (int r = 0; r < 4; ++r)
                atomicAdd(&outp[(size_t)(rowBase + frow0 + mm * 16 + lq * 4 + r) * 128
                                + aw * NA_N + lr], oacc[mm][r]);
    }
}

// ---------- launcher ----------
extern "C" void kernel_launch(void* const* d_in, const int* in_sizes, int n_in,
                              void* d_out, int out_size, void* d_ws, size_t ws_size,
                              hipStream_t stream) {
    const float* obs = (const float*)d_in[0];
    const float* act = (const float*)d_in[1];
    const float* W1 = (const float*)d_in[2];
    const float* b1 = (const float*)d_in[3];
    const float* W2 = (const float*)d_in[4];
    const float* b2 = (const float*)d_in[5];
    const float* W3 = (const float*)d_in[6];
    const float* b3 = (const float*)d_in[7];
    float* out = (float*)d_out;

    const size_t SZ_XB  = (size_t)B_SZ * IN_DD * 2;
    const size_t SZ_W1T = (size_t)NAGENT * H1_D * IN_DD * 2;
    const size_t SZ_W2T = (size_t)NAGENT * H1_D * H2_D * 2;
    const size_t SZ_W3T = (size_t)NAGENT * NA_N * H2_D * 2;
    const size_t SZ_H1  = (size_t)B_SZ * H1_D * 2;
    const size_t SZ_FIX = SZ_XB + SZ_W1T + SZ_W2T + SZ_W3T;

    char* ws = (char*)d_ws;
    bf16* Xb  = (bf16*)ws;
    bf16* W1T = (bf16*)(ws + SZ_XB);
    bf16* W2T = (bf16*)(ws + SZ_XB + SZ_W1T);
    bf16* W3T = (bf16*)(ws + SZ_XB + SZ_W1T + SZ_W2T);
    char* hbase = ws + SZ_FIX;

    // largest G (agents per pass) that fits: h1 only (h2/L3 fused)
    int G = 8;
    while (G > 1 && ws_size < SZ_FIX + (size_t)G * SZ_H1) G >>= 1;

    (void)hipFuncSetAttribute((const void*)k_gemm256<0>,
                              hipFuncAttributeMaxDynamicSharedMemorySize, 131072);
    (void)hipFuncSetAttribute((const void*)k_gemm256<1>,
                              hipFuncAttributeMaxDynamicSharedMemorySize, 131072);

    // fused preprocessing: X convert + out=b3 init + W3 transpose; merged W1/W2 transpose
    {
        const int NX = B_SZ * (IN_DD / 8);
        const int NO = B_SZ * 128 / 4;
        const int NW3 = NAGENT * NA_N * H2_D;
        int n = NX + NO + NW3;
        k_prep<<<(n + 255) / 256, 256, 0, stream>>>(obs, act, Xb, b3, out, W3, W3T);
    }
    k_transpose_w12<<<dim3(IN_DD / 32, 1024 / 32, 16), dim3(32, 8), 0, stream>>>(
        W1, W1T, W2, W2T);

    const size_t agElems = (size_t)B_SZ * H1_D;
    bf16* h1 = (bf16*)hbase;

    for (int g0 = 0; g0 < NAGENT; g0 += G) {
        k_gemm256<0><<<dim3(GRID_M, GRID_N, G), 512, 131072, stream>>>(
            Xb, 0, IN_DD, W1T, b1, h1, agElems, IN_DD, g0, G, nullptr, nullptr);
        k_gemm256<1><<<dim3(GRID_M, GRID_N, G), 512, 131072, stream>>>(
            h1, agElems, H1_D, W2T, b2, nullptr, 0, H1_D, g0, G, W3T, out);
    }
    (void)in_sizes; (void)n_in; (void)out_size;
}

// Round 15
// 418.671 us; speedup vs baseline: 1.2138x; 1.0554x over previous
//
#include <hip/hip_runtime.h>
#include <hip/hip_bf16.h>
#include <cstdint>
#include <cstddef>

typedef __bf16 bf16;
typedef __attribute__((ext_vector_type(8))) __bf16 bf16x8;
typedef __attribute__((ext_vector_type(4))) float f32x4;
typedef __attribute__((ext_vector_type(4))) int i32x4;
typedef __attribute__((address_space(3))) const bf16* lds_cp;

#define B_SZ  8192
#define NAGENT 8
#define NA_N  16
#define OBS_DD 2048
#define ACT_DD 128
#define IN_DD 2176
#define H1_D  1024
#define H2_D  1024

#define BM 256
#define BN 256
#define BK 64
#define GRID_M (B_SZ / BM)   // 32
#define GRID_N (1024 / BN)   // 4

__device__ __forceinline__ void gload16(const void* g, void* l) {
    __builtin_amdgcn_global_load_lds(
        (__attribute__((address_space(1))) void*)(g),
        (__attribute__((address_space(3))) void*)(l), 16, 0, 0);
}

// ---------- fused preprocessing (r13/r14-verified) ----------
__global__ void k_prep(const float* __restrict__ obs, const float* __restrict__ act,
                       bf16* __restrict__ xb, const float* __restrict__ b3,
                       float* __restrict__ out, const float* __restrict__ W3,
                       bf16* __restrict__ w3t) {
    const int NX = B_SZ * (IN_DD / 8);          // 2228224
    const int NO = B_SZ * 128 / 4;              // 262144 (float4)
    const int NW3 = NAGENT * NA_N * H2_D;       // 131072
    int idx = blockIdx.x * blockDim.x + threadIdx.x;
    if (idx < NX) {
        const int chunks = IN_DD / 8;
        int b = idx / chunks;
        int c8 = idx - b * chunks;
        const float* src = (c8 < OBS_DD / 8)
            ? (obs + (size_t)b * OBS_DD + c8 * 8)
            : (act + (size_t)b * ACT_DD + (c8 - OBS_DD / 8) * 8);
        float4 v0 = ((const float4*)src)[0];
        float4 v1 = ((const float4*)src)[1];
        bf16x8 o;
        o[0] = (bf16)v0.x; o[1] = (bf16)v0.y; o[2] = (bf16)v0.z; o[3] = (bf16)v0.w;
        o[4] = (bf16)v1.x; o[5] = (bf16)v1.y; o[6] = (bf16)v1.z; o[7] = (bf16)v1.w;
        ((bf16x8*)(xb + (size_t)b * IN_DD))[c8] = o;
    } else if (idx < NX + NO) {
        int i = idx - NX;
        int c = (i & 31) * 4;
        float4 v = make_float4(b3[c], b3[c + 1], b3[c + 2], b3[c + 3]);
        ((float4*)out)[i] = v;
    } else if (idx < NX + NO + NW3) {
        int i = idx - NX - NO;
        int a = i / (NA_N * H2_D);
        int n = (i / H2_D) % NA_N;
        int k = i % H2_D;
        w3t[i] = (bf16)W3[(size_t)a * H2_D * NA_N + (size_t)k * NA_N + n];
    }
}

// merged W1+W2 transpose (r14-verified): z<8 -> W1 (K=IN_DD, masked), z>=8 -> W2
__global__ void k_transpose_w12(const float* __restrict__ W1, bf16* __restrict__ W1T,
                                const float* __restrict__ W2, bf16* __restrict__ W2T) {
    __shared__ float tile[32][33];
    const int z = blockIdx.z;
    const bool isW1 = (z < 8);
    const int a = isW1 ? z : z - 8;
    const int K = isW1 ? IN_DD : H1_D;
    const int H = 1024;
    const int maskStart = isW1 ? OBS_DD : (1 << 30);
    if (!isW1 && blockIdx.x >= (H1_D / 32)) return;   // block-uniform, safe
    const float* s = (isW1 ? W1 : W2) + (size_t)a * K * H;
    bf16* d = (isW1 ? W1T : W2T) + (size_t)a * K * H;
    int k0 = blockIdx.x * 32, h0 = blockIdx.y * 32;
    int tx = threadIdx.x, ty = threadIdx.y;
    #pragma unroll
    for (int i = 0; i < 32; i += 8) {
        int k = k0 + ty + i;
        float v = s[(size_t)k * H + h0 + tx];
        if (k >= maskStart) {
            int g = k - maskStart;
            if ((g >> 4) == a) v = 0.f;
        }
        tile[ty + i][tx] = v;
    }
    __syncthreads();
    #pragma unroll
    for (int i = 0; i < 32; i += 8) {
        d[(size_t)(h0 + ty + i) * K + k0 + tx] = (bf16)tile[tx][ty + i];
    }
}

// ---------- 256x256x64 GEMM: r10 core, m-major clusters + ntile-fastest decode ----------
// Slots (elems): A: (t&1)*16384 ; B: 32768 + (t&1)*16384. 128 KiB total.
// Per K-tile per wave (ledger, in-order DS, all counted waits <= 8):
//   A01(4)+Bks0(4)+Bks1(4) issued [12]; STAGE 8 gloads (vm);
//   A23(4) [16]; lgkm(4)->C0(m0-1,16 MFMA); A45(4) [8]; lgkm(4)->C1(m2-3);
//   A67(4) [8]; lgkm(4)->C2(m4-5); vmcnt(0); lgkm(0)->C3(m6-7); barrier.
#define DSR4(d0, d1, d2, d3, addr, O0, O1, O2, O3)                      \
    asm volatile("ds_read_b128 %0, %4 offset:" #O0 "\n\t"               \
                 "ds_read_b128 %1, %4 offset:" #O1 "\n\t"               \
                 "ds_read_b128 %2, %4 offset:" #O2 "\n\t"               \
                 "ds_read_b128 %3, %4 offset:" #O3                      \
                 : "=&v"(d0), "=&v"(d1), "=&v"(d2), "=&v"(d3)           \
                 : "v"(addr))
#define DSR2(d0, d1, addr, O0, O1)                                      \
    asm volatile("ds_read_b128 %0, %2 offset:" #O0 "\n\t"               \
                 "ds_read_b128 %1, %2 offset:" #O1                      \
                 : "=&v"(d0), "=&v"(d1) : "v"(addr))

#define BC(x) __builtin_bit_cast(bf16x8, x)

template<int FUSE>
__global__ __launch_bounds__(512, 1)
void k_gemm256(const bf16* __restrict__ Ain, size_t aStride, int lda,
               const bf16* __restrict__ Bw, const float* __restrict__ bias,
               bf16* __restrict__ Cout, size_t cStride, int K,
               int aOff, int gridZ,
               const bf16* __restrict__ W3Tp, float* __restrict__ outp) {
    extern __shared__ bf16 lds[];   // 65536 elems = 128 KiB

    const int tid = threadIdx.x;
    const int w = tid >> 6;
    const int l = tid & 63;

    // XCD-chunked remap (nwg = 128*gridZ, % 8 == 0).
    // r15 change: ntile FASTEST within chunk -> each A-strip (1.1 MB, L2-resident)
    // is reused across the 4 ntile blocks before advancing mt; B stays chunk-local.
    int flat = blockIdx.x + GRID_M * (blockIdx.y + GRID_N * blockIdx.z);
    int q8 = (GRID_M * GRID_N * gridZ) >> 3;
    int lin2 = (flat & 7) * q8 + (flat >> 3);
    const int ntile = lin2 % GRID_N;
    int rest = lin2 / GRID_N;
    const int mt = rest % GRID_M;
    const int az = rest / GRID_M;
    const int aw = az + aOff;

    const int rowBase = mt * BM;
    const int colBase = ntile * BN;
    const bf16* Aag = Ain + (size_t)az * aStride;
    const bf16* Bag = Bw + (size_t)aw * (size_t)1024 * K;

    const int wr = (w >> 2) * 128;   // wave rows (2M)
    const int wc = (w & 3) * 64;     // wave cols (4N)
    const int lr = l & 15;
    const int lq = l >> 4;

    // fragment addressing (r3/r6/r10-verified): phys chunk = logical ^ (row & 7)
    const int rowA = (wr + lr) * BK;
    const int rowB = (wc + lr) * BK;
    const int ck0 = ((lq ^ (lr & 7)) * 8);
    const int ck1 = (((4 + lq) ^ (lr & 7)) * 8);

    // staging (r3/r10-verified): lane -> row w*16+(l>>3), pre-swizzled col
    const int sRow = w * 16 + (l >> 3);
    const int sCol = ((l & 7) ^ (l >> 3)) * 8;
    const bf16* pA0 = Aag + (size_t)(rowBase + sRow) * lda + sCol;
    const bf16* pA1 = Aag + (size_t)(rowBase + 128 + sRow) * lda + sCol;
    const bf16* pB0 = Bag + (size_t)(colBase + sRow) * K + sCol;
    const bf16* pB1 = Bag + (size_t)(colBase + 128 + sRow) * K + sCol;
    const size_t l8a = (size_t)8 * lda;
    const size_t l8b = (size_t)8 * K;

    const int nkt = K / BK;

#define STAGE_A(t1, half) do {                                              \
        const bf16* g_ = ((half) ? pA1 : pA0) + (t1) * BK;                  \
        bf16* d_ = &lds[(((t1) & 1) * 16384) + (half) * 8192 + w * 1024];   \
        gload16(g_, d_);                                                    \
        gload16(g_ + l8a, d_ + 512);                                        \
    } while (0)
#define STAGE_B(t2, half) do {                                              \
        const bf16* g_ = ((half) ? pB1 : pB0) + (t2) * BK;                  \
        bf16* d_ = &lds[32768 + (((t2) & 1) * 16384) + (half) * 8192 + w * 1024]; \
        gload16(g_, d_);                                                    \
        gload16(g_ + l8b, d_ + 512);                                        \
    } while (0)

    f32x4 acc[8][4] = {};
    i32x4 rb0, rb1, rb2, rb3, rb4, rb5, rb6, rb7;   // B ks0 (0-3), ks1 (4-7)
    i32x4 pa0, pa1, pa2, pa3;   // A m-pair P: {m,m+1} x {ks0,ks1}
    i32x4 qa0, qa1, qa2, qa3;   // A m-pair Q

// 16 MFMA: m-pair (M0,M0+1) x 4n x 2ks. a0=A(M0,ks0) a1=A(M0+1,ks0) a2=A(M0,ks1) a3=A(M0+1,ks1)
#define CLUST(M0, a0, a1, a2, a3)                                           \
    do {                                                                    \
        acc[M0+0][0] = __builtin_amdgcn_mfma_f32_16x16x32_bf16(BC(a0), BC(rb0), acc[M0+0][0], 0, 0, 0); \
        acc[M0+1][0] = __builtin_amdgcn_mfma_f32_16x16x32_bf16(BC(a1), BC(rb0), acc[M0+1][0], 0, 0, 0); \
        acc[M0+0][1] = __builtin_amdgcn_mfma_f32_16x16x32_bf16(BC(a0), BC(rb1), acc[M0+0][1], 0, 0, 0); \
        acc[M0+1][1] = __builtin_amdgcn_mfma_f32_16x16x32_bf16(BC(a1), BC(rb1), acc[M0+1][1], 0, 0, 0); \
        acc[M0+0][2] = __builtin_amdgcn_mfma_f32_16x16x32_bf16(BC(a0), BC(rb2), acc[M0+0][2], 0, 0, 0); \
        acc[M0+1][2] = __builtin_amdgcn_mfma_f32_16x16x32_bf16(BC(a1), BC(rb2), acc[M0+1][2], 0, 0, 0); \
        acc[M0+0][3] = __builtin_amdgcn_mfma_f32_16x16x32_bf16(BC(a0), BC(rb3), acc[M0+0][3], 0, 0, 0); \
        acc[M0+1][3] = __builtin_amdgcn_mfma_f32_16x16x32_bf16(BC(a1), BC(rb3), acc[M0+1][3], 0, 0, 0); \
        acc[M0+0][0] = __builtin_amdgcn_mfma_f32_16x16x32_bf16(BC(a2), BC(rb4), acc[M0+0][0], 0, 0, 0); \
        acc[M0+1][0] = __builtin_amdgcn_mfma_f32_16x16x32_bf16(BC(a3), BC(rb4), acc[M0+1][0], 0, 0, 0); \
        acc[M0+0][1] = __builtin_amdgcn_mfma_f32_16x16x32_bf16(BC(a2), BC(rb5), acc[M0+0][1], 0, 0, 0); \
        acc[M0+1][1] = __builtin_amdgcn_mfma_f32_16x16x32_bf16(BC(a3), BC(rb5), acc[M0+1][1], 0, 0, 0); \
        acc[M0+0][2] = __builtin_amdgcn_mfma_f32_16x16x32_bf16(BC(a2), BC(rb6), acc[M0+0][2], 0, 0, 0); \
        acc[M0+1][2] = __builtin_amdgcn_mfma_f32_16x16x32_bf16(BC(a3), BC(rb6), acc[M0+1][2], 0, 0, 0); \
        acc[M0+0][3] = __builtin_amdgcn_mfma_f32_16x16x32_bf16(BC(a2), BC(rb7), acc[M0+0][3], 0, 0, 0); \
        acc[M0+1][3] = __builtin_amdgcn_mfma_f32_16x16x32_bf16(BC(a3), BC(rb7), acc[M0+1][3], 0, 0, 0); \
    } while (0)

    // prologue: stage tile 0, drain, barrier
    STAGE_A(0, 0); STAGE_A(0, 1);
    STAGE_B(0, 0); STAGE_B(0, 1);
    asm volatile("s_waitcnt vmcnt(0)" ::: "memory");
    __builtin_amdgcn_s_barrier();

    for (int t = 0; t < nkt; ++t) {
        const int dbuf = (t & 1) * 16384;
        lds_cp adrA0 = (lds_cp)lds + (dbuf + rowA + ck0);
        lds_cp adrA1 = (lds_cp)lds + (dbuf + rowA + ck1);
        lds_cp adrB0 = (lds_cp)lds + (32768 + dbuf + rowB + ck0);
        lds_cp adrB1 = (lds_cp)lds + (32768 + dbuf + rowB + ck1);

        // A m0,m1 (both ks) + B (both ks): 12 reads
        DSR2(pa0, pa1, adrA0, 0, 2048);
        DSR2(pa2, pa3, adrA1, 0, 2048);
        DSR4(rb0, rb1, rb2, rb3, adrB0, 0, 2048, 4096, 6144);
        DSR4(rb4, rb5, rb6, rb7, adrB1, 0, 2048, 4096, 6144);

        // stage next tile (vmcnt-counted only; lands during the MFMA body)
        if (t + 1 < nkt) {
            STAGE_A(t + 1, 0); STAGE_A(t + 1, 1);
            STAGE_B(t + 1, 0); STAGE_B(t + 1, 1);
        }

        // A m2,m3: 4 reads [16 outstanding]
        DSR2(qa0, qa1, adrA0, 4096, 6144);
        DSR2(qa2, qa3, adrA1, 4096, 6144);

        asm volatile("s_waitcnt lgkmcnt(4)" ::: "memory");   // A01+B done
        __builtin_amdgcn_sched_barrier(0);
        __builtin_amdgcn_s_setprio(1);
        CLUST(0, pa0, pa1, pa2, pa3);                        // m0-1
        __builtin_amdgcn_s_setprio(0);

        // A m4,m5 [8 out]
        DSR2(pa0, pa1, adrA0, 8192, 10240);
        DSR2(pa2, pa3, adrA1, 8192, 10240);

        asm volatile("s_waitcnt lgkmcnt(4)" ::: "memory");   // A23 done
        __builtin_amdgcn_sched_barrier(0);
        __builtin_amdgcn_s_setprio(1);
        CLUST(2, qa0, qa1, qa2, qa3);                        // m2-3
        __builtin_amdgcn_s_setprio(0);

        // A m6,m7 [8 out]
        DSR2(qa0, qa1, adrA0, 12288, 14336);
        DSR2(qa2, qa3, adrA1, 12288, 14336);

        asm volatile("s_waitcnt lgkmcnt(4)" ::: "memory");   // A45 done
        __builtin_amdgcn_sched_barrier(0);
        __builtin_amdgcn_s_setprio(1);
        CLUST(4, pa0, pa1, pa2, pa3);                        // m4-5
        __builtin_amdgcn_s_setprio(0);

        asm volatile("s_waitcnt vmcnt(0)" ::: "memory");     // stage(t+1) drained
        asm volatile("s_waitcnt lgkmcnt(0)" ::: "memory");   // A67 done
        __builtin_amdgcn_sched_barrier(0);
        __builtin_amdgcn_s_setprio(1);
        CLUST(6, qa0, qa1, qa2, qa3);                        // m6-7
        __builtin_amdgcn_s_setprio(0);

        __builtin_amdgcn_s_barrier();
    }
#undef STAGE_A
#undef STAGE_B
#undef CLUST

    // ---- epilogue: bias + relu -> swizzled C-LDS tile [256][256] bf16 (r3-verified)
    __syncthreads();
    const float* bAg = bias + (size_t)aw * 1024;
    float bb4[4];
    #pragma unroll
    for (int n = 0; n < 4; ++n) bb4[n] = bAg[colBase + wc + n * 16 + lr];
    #pragma unroll
    for (int m = 0; m < 8; ++m)
        #pragma unroll
        for (int n = 0; n < 4; ++n)
            #pragma unroll
            for (int r = 0; r < 4; ++r) {
                float v = acc[m][n][r] + bb4[n];
                v = fmaxf(v, 0.f);
                int row = wr + m * 16 + lq * 4 + r;
                int col = wc + n * 16 + lr;
                lds[row * 256 + ((((col >> 3) ^ (row & 7)) << 3) | (col & 7))] = (bf16)v;
            }
    __syncthreads();

    if constexpr (!FUSE) {
        bf16* Cg = Cout + (size_t)az * cStride + (size_t)rowBase * 1024 + colBase;
        const int er = tid >> 5;
        const int ec = tid & 31;
        #pragma unroll
        for (int i = 0; i < 16; ++i) {
            int row = i * 16 + er;
            int phys = ec ^ (row & 7);
            *(bf16x8*)&Cg[(size_t)row * 1024 + ec * 8] =
                *(const bf16x8*)&lds[row * 256 + phys * 8];
        }
    } else {
        // fused L3 (r3-verified): h2 tile x W3T[aw] -> atomicAdd into out
        const bf16* w3a = W3Tp + (size_t)aw * NA_N * H2_D;
        f32x4 oacc[2] = {};
        const int frow0 = w * 32;
        #pragma unroll
        for (int ks = 0; ks < 8; ++ks) {
            bf16x8 bfrag = *(const bf16x8*)&w3a[(size_t)lr * H2_D + colBase + ks * 32 + lq * 8];
            #pragma unroll
            for (int mm = 0; mm < 2; ++mm) {
                int row = frow0 + mm * 16 + lr;
                int lc = (ks * 4 + lq) ^ (row & 7);
                bf16x8 afrag = *(const bf16x8*)&lds[row * 256 + lc * 8];
                oacc[mm] = __builtin_amdgcn_mfma_f32_16x16x32_bf16(afrag, bfrag, oacc[mm], 0, 0, 0);
            }
        }
        #pragma unroll
        for (int mm = 0; mm < 2; ++mm)
            #pragma unroll
            for (int r = 0; r < 4; ++r)
                atomicAdd(&outp[(size_t)(rowBase + frow0 + mm * 16 + lq * 4 + r) * 128
                                + aw * NA_N + lr], oacc[mm][r]);
    }
}

// ---------- launcher ----------
extern "C" void kernel_launch(void* const* d_in, const int* in_sizes, int n_in,
                              void* d_out, int out_size, void* d_ws, size_t ws_size,
                              hipStream_t stream) {
    const float* obs = (const float*)d_in[0];
    const float* act = (const float*)d_in[1];
    const float* W1 = (const float*)d_in[2];
    const float* b1 = (const float*)d_in[3];
    const float* W2 = (const float*)d_in[4];
    const float* b2 = (const float*)d_in[5];
    const float* W3 = (const float*)d_in[6];
    const float* b3 = (const float*)d_in[7];
    float* out = (float*)d_out;

    const size_t SZ_XB  = (size_t)B_SZ * IN_DD * 2;
    const size_t SZ_W1T = (size_t)NAGENT * H1_D * IN_DD * 2;
    const size_t SZ_W2T = (size_t)NAGENT * H1_D * H2_D * 2;
    const size_t SZ_W3T = (size_t)NAGENT * NA_N * H2_D * 2;
    const size_t SZ_H1  = (size_t)B_SZ * H1_D * 2;
    const size_t SZ_FIX = SZ_XB + SZ_W1T + SZ_W2T + SZ_W3T;

    char* ws = (char*)d_ws;
    bf16* Xb  = (bf16*)ws;
    bf16* W1T = (bf16*)(ws + SZ_XB);
    bf16* W2T = (bf16*)(ws + SZ_XB + SZ_W1T);
    bf16* W3T = (bf16*)(ws + SZ_XB + SZ_W1T + SZ_W2T);
    char* hbase = ws + SZ_FIX;

    // largest G (agents per pass) that fits: h1 only (h2/L3 fused)
    int G = 8;
    while (G > 1 && ws_size < SZ_FIX + (size_t)G * SZ_H1) G >>= 1;

    (void)hipFuncSetAttribute((const void*)k_gemm256<0>,
                              hipFuncAttributeMaxDynamicSharedMemorySize, 131072);
    (void)hipFuncSetAttribute((const void*)k_gemm256<1>,
                              hipFuncAttributeMaxDynamicSharedMemorySize, 131072);

    // fused preprocessing + merged W1/W2 transpose (r14-verified)
    {
        const int NX = B_SZ * (IN_DD / 8);
        const int NO = B_SZ * 128 / 4;
        const int NW3 = NAGENT * NA_N * H2_D;
        int n = NX + NO + NW3;
        k_prep<<<(n + 255) / 256, 256, 0, stream>>>(obs, act, Xb, b3, out, W3, W3T);
    }
    k_transpose_w12<<<dim3(IN_DD / 32, 1024 / 32, 16), dim3(32, 8), 0, stream>>>(
        W1, W1T, W2, W2T);

    const size_t agElems = (size_t)B_SZ * H1_D;
    bf16* h1 = (bf16*)hbase;

    for (int g0 = 0; g0 < NAGENT; g0 += G) {
        k_gemm256<0><<<dim3(GRID_M, GRID_N, G), 512, 131072, stream>>>(
            Xb, 0, IN_DD, W1T, b1, h1, agElems, IN_DD, g0, G, nullptr, nullptr);
        k_gemm256<1><<<dim3(GRID_M, GRID_N, G), 512, 131072, stream>>>(
            h1, agElems, H1_D, W2T, b2, nullptr, 0, H1_D, g0, G, W3T, out);
    }
    (void)in_sizes; (void)n_in; (void)out_size;
}

// Round 16
// 407.056 us; speedup vs baseline: 1.2484x; 1.0285x over previous
//
#include <hip/hip_runtime.h>
#include <hip/hip_bf16.h>
#include <cstdint>
#include <cstddef>

typedef __bf16 bf16;
typedef __attribute__((ext_vector_type(8))) __bf16 bf16x8;
typedef __attribute__((ext_vector_type(4))) float f32x4;
typedef __attribute__((ext_vector_type(4))) int i32x4;
typedef __attribute__((address_space(3))) const bf16* lds_cp;

#define B_SZ  8192
#define NAGENT 8
#define NA_N  16
#define OBS_DD 2048
#define ACT_DD 128
#define IN_DD 2176
#define H1_D  1024
#define H2_D  1024

#define BM 256
#define BN 256
#define BK 64
#define GRID_M (B_SZ / BM)   // 32
#define GRID_N (1024 / BN)   // 4

__device__ __forceinline__ void gload16(const void* g, void* l) {
    __builtin_amdgcn_global_load_lds(
        (__attribute__((address_space(1))) void*)(g),
        (__attribute__((address_space(3))) void*)(l), 16, 0, 0);
}

// ---------- fused preprocessing (r13/r14-verified) ----------
__global__ void k_prep(const float* __restrict__ obs, const float* __restrict__ act,
                       bf16* __restrict__ xb, const float* __restrict__ b3,
                       float* __restrict__ out, const float* __restrict__ W3,
                       bf16* __restrict__ w3t) {
    const int NX = B_SZ * (IN_DD / 8);          // 2228224
    const int NO = B_SZ * 128 / 4;              // 262144 (float4)
    const int NW3 = NAGENT * NA_N * H2_D;       // 131072
    int idx = blockIdx.x * blockDim.x + threadIdx.x;
    if (idx < NX) {
        const int chunks = IN_DD / 8;
        int b = idx / chunks;
        int c8 = idx - b * chunks;
        const float* src = (c8 < OBS_DD / 8)
            ? (obs + (size_t)b * OBS_DD + c8 * 8)
            : (act + (size_t)b * ACT_DD + (c8 - OBS_DD / 8) * 8);
        float4 v0 = ((const float4*)src)[0];
        float4 v1 = ((const float4*)src)[1];
        bf16x8 o;
        o[0] = (bf16)v0.x; o[1] = (bf16)v0.y; o[2] = (bf16)v0.z; o[3] = (bf16)v0.w;
        o[4] = (bf16)v1.x; o[5] = (bf16)v1.y; o[6] = (bf16)v1.z; o[7] = (bf16)v1.w;
        ((bf16x8*)(xb + (size_t)b * IN_DD))[c8] = o;
    } else if (idx < NX + NO) {
        int i = idx - NX;
        int c = (i & 31) * 4;
        float4 v = make_float4(b3[c], b3[c + 1], b3[c + 2], b3[c + 3]);
        ((float4*)out)[i] = v;
    } else if (idx < NX + NO + NW3) {
        int i = idx - NX - NO;
        int a = i / (NA_N * H2_D);
        int n = (i / H2_D) % NA_N;
        int k = i % H2_D;
        w3t[i] = (bf16)W3[(size_t)a * H2_D * NA_N + (size_t)k * NA_N + n];
    }
}

// merged W1+W2 transpose (r14-verified)
__global__ void k_transpose_w12(const float* __restrict__ W1, bf16* __restrict__ W1T,
                                const float* __restrict__ W2, bf16* __restrict__ W2T) {
    __shared__ float tile[32][33];
    const int z = blockIdx.z;
    const bool isW1 = (z < 8);
    const int a = isW1 ? z : z - 8;
    const int K = isW1 ? IN_DD : H1_D;
    const int H = 1024;
    const int maskStart = isW1 ? OBS_DD : (1 << 30);
    if (!isW1 && blockIdx.x >= (H1_D / 32)) return;   // block-uniform, safe
    const float* s = (isW1 ? W1 : W2) + (size_t)a * K * H;
    bf16* d = (isW1 ? W1T : W2T) + (size_t)a * K * H;
    int k0 = blockIdx.x * 32, h0 = blockIdx.y * 32;
    int tx = threadIdx.x, ty = threadIdx.y;
    #pragma unroll
    for (int i = 0; i < 32; i += 8) {
        int k = k0 + ty + i;
        float v = s[(size_t)k * H + h0 + tx];
        if (k >= maskStart) {
            int g = k - maskStart;
            if ((g >> 4) == a) v = 0.f;
        }
        tile[ty + i][tx] = v;
    }
    __syncthreads();
    #pragma unroll
    for (int i = 0; i < 32; i += 8) {
        d[(size_t)(h0 + ty + i) * K + k0 + tx] = (bf16)tile[tx][ty + i];
    }
}

// ---------- 256x256x64 GEMM: ks-split 8-cluster schedule, ntile-fastest decode ----------
// Slots (elems): A: (t&1)*16384 ; B: 32768 + (t&1)*16384. 128 KiB total.
// Per K-tile per wave (in-order DS ledger; counted waits <= 6):
//   A01k0(2)+Bk0(4) [6]; A23k0(2) [8]; lgkm(2)->CL(m01,k0); A45k0(2) [4];
//   lgkm(2)->CL(m23,k0); A67k0(2) [4]; STAGE(8 gloads, vm); lgkm(2)->CL(m45,k0);
//   A01k1(2)+Bk1(4) [8]; lgkm(6)->CL(m67,k0); A23k1(2) [8]; lgkm(2)->CL(m01,k1);
//   A45k1(2) [4]; lgkm(2)->CL(m23,k1); A67k1(2) [4]; lgkm(2)->CL(m45,k1);
//   vmcnt(0); lgkm(0)->CL(m67,k1); barrier.
#define DSR4(d0, d1, d2, d3, addr, O0, O1, O2, O3)                      \
    asm volatile("ds_read_b128 %0, %4 offset:" #O0 "\n\t"               \
                 "ds_read_b128 %1, %4 offset:" #O1 "\n\t"               \
                 "ds_read_b128 %2, %4 offset:" #O2 "\n\t"               \
                 "ds_read_b128 %3, %4 offset:" #O3                      \
                 : "=&v"(d0), "=&v"(d1), "=&v"(d2), "=&v"(d3)           \
                 : "v"(addr))
#define DSR2(d0, d1, addr, O0, O1)                                      \
    asm volatile("ds_read_b128 %0, %2 offset:" #O0 "\n\t"               \
                 "ds_read_b128 %1, %2 offset:" #O1                      \
                 : "=&v"(d0), "=&v"(d1) : "v"(addr))

#define BC(x) __builtin_bit_cast(bf16x8, x)

template<int FUSE>
__global__ __launch_bounds__(512, 1)
void k_gemm256(const bf16* __restrict__ Ain, size_t aStride, int lda,
               const bf16* __restrict__ Bw, const float* __restrict__ bias,
               bf16* __restrict__ Cout, size_t cStride, int K,
               int aOff, int gridZ,
               const bf16* __restrict__ W3Tp, float* __restrict__ outp) {
    extern __shared__ bf16 lds[];   // 65536 elems = 128 KiB

    const int tid = threadIdx.x;
    const int w = tid >> 6;
    const int l = tid & 63;

    // XCD-chunked remap, ntile FASTEST (r15-verified: FETCH 574->209 MB)
    int flat = blockIdx.x + GRID_M * (blockIdx.y + GRID_N * blockIdx.z);
    int q8 = (GRID_M * GRID_N * gridZ) >> 3;
    int lin2 = (flat & 7) * q8 + (flat >> 3);
    const int ntile = lin2 % GRID_N;
    int rest = lin2 / GRID_N;
    const int mt = rest % GRID_M;
    const int az = rest / GRID_M;
    const int aw = az + aOff;

    const int rowBase = mt * BM;
    const int colBase = ntile * BN;
    const bf16* Aag = Ain + (size_t)az * aStride;
    const bf16* Bag = Bw + (size_t)aw * (size_t)1024 * K;

    const int wr = (w >> 2) * 128;   // wave rows (2M)
    const int wc = (w & 3) * 64;     // wave cols (4N)
    const int lr = l & 15;
    const int lq = l >> 4;

    // fragment addressing (r3/r6/r10-verified): phys chunk = logical ^ (row & 7)
    const int rowA = (wr + lr) * BK;
    const int rowB = (wc + lr) * BK;
    const int ck0 = ((lq ^ (lr & 7)) * 8);
    const int ck1 = (((4 + lq) ^ (lr & 7)) * 8);

    // staging (r3/r10-verified): lane -> row w*16+(l>>3), pre-swizzled col
    const int sRow = w * 16 + (l >> 3);
    const int sCol = ((l & 7) ^ (l >> 3)) * 8;
    const bf16* pA0 = Aag + (size_t)(rowBase + sRow) * lda + sCol;
    const bf16* pA1 = Aag + (size_t)(rowBase + 128 + sRow) * lda + sCol;
    const bf16* pB0 = Bag + (size_t)(colBase + sRow) * K + sCol;
    const bf16* pB1 = Bag + (size_t)(colBase + 128 + sRow) * K + sCol;
    const size_t l8a = (size_t)8 * lda;
    const size_t l8b = (size_t)8 * K;

    const int nkt = K / BK;

#define STAGE_A(t1, half) do {                                              \
        const bf16* g_ = ((half) ? pA1 : pA0) + (t1) * BK;                  \
        bf16* d_ = &lds[(((t1) & 1) * 16384) + (half) * 8192 + w * 1024];   \
        gload16(g_, d_);                                                    \
        gload16(g_ + l8a, d_ + 512);                                        \
    } while (0)
#define STAGE_B(t2, half) do {                                              \
        const bf16* g_ = ((half) ? pB1 : pB0) + (t2) * BK;                  \
        bf16* d_ = &lds[32768 + (((t2) & 1) * 16384) + (half) * 8192 + w * 1024]; \
        gload16(g_, d_);                                                    \
        gload16(g_ + l8b, d_ + 512);                                        \
    } while (0)

    f32x4 acc[8][4] = {};
    i32x4 rb0, rb1, rb2, rb3, rb4, rb5, rb6, rb7;   // B ks0 (0-3), ks1 (4-7)
    i32x4 a0, a1, a2, a3, a4, a5, a6, a7, z0, z1;   // A frag regs (rotating)

// 8 MFMA: m-pair (M0,M0+1) x 4n at one ks (B regs Bx0..Bx3)
#define CL8(M0, A0r, A1r, Bx0, Bx1, Bx2, Bx3)                               \
    do {                                                                    \
        acc[M0+0][0] = __builtin_amdgcn_mfma_f32_16x16x32_bf16(BC(A0r), BC(Bx0), acc[M0+0][0], 0, 0, 0); \
        acc[M0+1][0] = __builtin_amdgcn_mfma_f32_16x16x32_bf16(BC(A1r), BC(Bx0), acc[M0+1][0], 0, 0, 0); \
        acc[M0+0][1] = __builtin_amdgcn_mfma_f32_16x16x32_bf16(BC(A0r), BC(Bx1), acc[M0+0][1], 0, 0, 0); \
        acc[M0+1][1] = __builtin_amdgcn_mfma_f32_16x16x32_bf16(BC(A1r), BC(Bx1), acc[M0+1][1], 0, 0, 0); \
        acc[M0+0][2] = __builtin_amdgcn_mfma_f32_16x16x32_bf16(BC(A0r), BC(Bx2), acc[M0+0][2], 0, 0, 0); \
        acc[M0+1][2] = __builtin_amdgcn_mfma_f32_16x16x32_bf16(BC(A1r), BC(Bx2), acc[M0+1][2], 0, 0, 0); \
        acc[M0+0][3] = __builtin_amdgcn_mfma_f32_16x16x32_bf16(BC(A0r), BC(Bx3), acc[M0+0][3], 0, 0, 0); \
        acc[M0+1][3] = __builtin_amdgcn_mfma_f32_16x16x32_bf16(BC(A1r), BC(Bx3), acc[M0+1][3], 0, 0, 0); \
    } while (0)

#define WAITL(N)                                                            \
    asm volatile("s_waitcnt lgkmcnt(" #N ")" ::: "memory");                 \
    __builtin_amdgcn_sched_barrier(0)

    // prologue: stage tile 0, drain, barrier
    STAGE_A(0, 0); STAGE_A(0, 1);
    STAGE_B(0, 0); STAGE_B(0, 1);
    asm volatile("s_waitcnt vmcnt(0)" ::: "memory");
    __builtin_amdgcn_s_barrier();

    for (int t = 0; t < nkt; ++t) {
        const int dbuf = (t & 1) * 16384;
        lds_cp adrA0 = (lds_cp)lds + (dbuf + rowA + ck0);
        lds_cp adrA1 = (lds_cp)lds + (dbuf + rowA + ck1);
        lds_cp adrB0 = (lds_cp)lds + (32768 + dbuf + rowB + ck0);
        lds_cp adrB1 = (lds_cp)lds + (32768 + dbuf + rowB + ck1);

        // cold window: only the 6 reads cluster-0 needs, plus next pair
        DSR2(a0, a1, adrA0, 0, 2048);                    // A01 ks0      [2]
        DSR4(rb0, rb1, rb2, rb3, adrB0, 0, 2048, 4096, 6144);  // B ks0  [6]
        DSR2(a2, a3, adrA0, 4096, 6144);                 // A23 ks0      [8]

        WAITL(2);                                        // A01+B done
        __builtin_amdgcn_s_setprio(1);
        CL8(0, a0, a1, rb0, rb1, rb2, rb3);              // m01 ks0
        __builtin_amdgcn_s_setprio(0);

        DSR2(a4, a5, adrA0, 8192, 10240);                // A45 ks0      [4]
        WAITL(2);                                        // A23 done
        __builtin_amdgcn_s_setprio(1);
        CL8(2, a2, a3, rb0, rb1, rb2, rb3);              // m23 ks0
        __builtin_amdgcn_s_setprio(0);

        DSR2(a6, a7, adrA0, 12288, 14336);               // A67 ks0      [4]
        // stage next tile OUT of the cold window (under MFMA); vm-counted only
        if (t + 1 < nkt) {
            STAGE_A(t + 1, 0); STAGE_A(t + 1, 1);
            STAGE_B(t + 1, 0); STAGE_B(t + 1, 1);
        }
        WAITL(2);                                        // A45 done
        __builtin_amdgcn_s_setprio(1);
        CL8(4, a4, a5, rb0, rb1, rb2, rb3);              // m45 ks0
        __builtin_amdgcn_s_setprio(0);

        DSR2(z0, z1, adrA1, 0, 2048);                    // A01 ks1      [4]
        DSR4(rb4, rb5, rb6, rb7, adrB1, 0, 2048, 4096, 6144);  // B ks1  [8]
        WAITL(6);                                        // A67 done
        __builtin_amdgcn_s_setprio(1);
        CL8(6, a6, a7, rb0, rb1, rb2, rb3);              // m67 ks0
        __builtin_amdgcn_s_setprio(0);

        DSR2(a0, a1, adrA1, 4096, 6144);                 // A23 ks1      [8]
        WAITL(2);                                        // A01k1+Bk1 done
        __builtin_amdgcn_s_setprio(1);
        CL8(0, z0, z1, rb4, rb5, rb6, rb7);              // m01 ks1
        __builtin_amdgcn_s_setprio(0);

        DSR2(a2, a3, adrA1, 8192, 10240);                // A45 ks1      [4]
        WAITL(2);                                        // A23k1 done
        __builtin_amdgcn_s_setprio(1);
        CL8(2, a0, a1, rb4, rb5, rb6, rb7);              // m23 ks1
        __builtin_amdgcn_s_setprio(0);

        DSR2(a4, a5, adrA1, 12288, 14336);               // A67 ks1      [4]
        WAITL(2);                                        // A45k1 done
        __builtin_amdgcn_s_setprio(1);
        CL8(4, a2, a3, rb4, rb5, rb6, rb7);              // m45 ks1
        __builtin_amdgcn_s_setprio(0);

        asm volatile("s_waitcnt vmcnt(0)" ::: "memory"); // stage(t+1) drained
        WAITL(0);                                        // A67k1 done
        __builtin_amdgcn_s_setprio(1);
        CL8(6, a4, a5, rb4, rb5, rb6, rb7);              // m67 ks1
        __builtin_amdgcn_s_setprio(0);

        __builtin_amdgcn_s_barrier();
    }
#undef STAGE_A
#undef STAGE_B
#undef CL8
#undef WAITL

    // ---- epilogue: bias + relu -> swizzled C-LDS tile [256][256] bf16 (r3-verified)
    __syncthreads();
    const float* bAg = bias + (size_t)aw * 1024;
    float bb4[4];
    #pragma unroll
    for (int n = 0; n < 4; ++n) bb4[n] = bAg[colBase + wc + n * 16 + lr];
    #pragma unroll
    for (int m = 0; m < 8; ++m)
        #pragma unroll
        for (int n = 0; n < 4; ++n)
            #pragma unroll
            for (int r = 0; r < 4; ++r) {
                float v = acc[m][n][r] + bb4[n];
                v = fmaxf(v, 0.f);
                int row = wr + m * 16 + lq * 4 + r;
                int col = wc + n * 16 + lr;
                lds[row * 256 + ((((col >> 3) ^ (row & 7)) << 3) | (col & 7))] = (bf16)v;
            }
    __syncthreads();

    if constexpr (!FUSE) {
        bf16* Cg = Cout + (size_t)az * cStride + (size_t)rowBase * 1024 + colBase;
        const int er = tid >> 5;
        const int ec = tid & 31;
        #pragma unroll
        for (int i = 0; i < 16; ++i) {
            int row = i * 16 + er;
            int phys = ec ^ (row & 7);
            *(bf16x8*)&Cg[(size_t)row * 1024 + ec * 8] =
                *(const bf16x8*)&lds[row * 256 + phys * 8];
        }
    } else {
        // fused L3 (r3-verified): h2 tile x W3T[aw] -> atomicAdd into out
        const bf16* w3a = W3Tp + (size_t)aw * NA_N * H2_D;
        f32x4 oacc[2] = {};
        const int frow0 = w * 32;
        #pragma unroll
        for (int ks = 0; ks < 8; ++ks) {
            bf16x8 bfrag = *(const bf16x8*)&w3a[(size_t)lr * H2_D + colBase + ks * 32 + lq * 8];
            #pragma unroll
            for (int mm = 0; mm < 2; ++mm) {
                int row = frow0 + mm * 16 + lr;
                int lc = (ks * 4 + lq) ^ (row & 7);
                bf16x8 afrag = *(const bf16x8*)&lds[row * 256 + lc * 8];
                oacc[mm] = __builtin_amdgcn_mfma_f32_16x16x32_bf16(afrag, bfrag, oacc[mm], 0, 0, 0);
            }
        }
        #pragma unroll
        for (int mm = 0; mm < 2; ++mm)
            #pragma unroll
            for (int r = 0; r < 4; ++r)
                atomicAdd(&outp[(size_t)(rowBase + frow0 + mm * 16 + lq * 4 + r) * 128
                                + aw * NA_N + lr], oacc[mm][r]);
    }
}

// ---------- launcher ----------
extern "C" void kernel_launch(void* const* d_in, const int* in_sizes, int n_in,
                              void* d_out, int out_size, void* d_ws, size_t ws_size,
                              hipStream_t stream) {
    const float* obs = (const float*)d_in[0];
    const float* act = (const float*)d_in[1];
    const float* W1 = (const float*)d_in[2];
    const float* b1 = (const float*)d_in[3];
    const float* W2 = (const float*)d_in[4];
    const float* b2 = (const float*)d_in[5];
    const float* W3 = (const float*)d_in[6];
    const float* b3 = (const float*)d_in[7];
    float* out = (float*)d_out;

    const size_t SZ_XB  = (size_t)B_SZ * IN_DD * 2;
    const size_t SZ_W1T = (size_t)NAGENT * H1_D * IN_DD * 2;
    const size_t SZ_W2T = (size_t)NAGENT * H1_D * H2_D * 2;
    const size_t SZ_W3T = (size_t)NAGENT * NA_N * H2_D * 2;
    const size_t SZ_H1  = (size_t)B_SZ * H1_D * 2;
    const size_t SZ_FIX = SZ_XB + SZ_W1T + SZ_W2T + SZ_W3T;

    char* ws = (char*)d_ws;
    bf16* Xb  = (bf16*)ws;
    bf16* W1T = (bf16*)(ws + SZ_XB);
    bf16* W2T = (bf16*)(ws + SZ_XB + SZ_W1T);
    bf16* W3T = (bf16*)(ws + SZ_XB + SZ_W1T + SZ_W2T);
    char* hbase = ws + SZ_FIX;

    // largest G (agents per pass) that fits: h1 only (h2/L3 fused)
    int G = 8;
    while (G > 1 && ws_size < SZ_FIX + (size_t)G * SZ_H1) G >>= 1;

    (void)hipFuncSetAttribute((const void*)k_gemm256<0>,
                              hipFuncAttributeMaxDynamicSharedMemorySize, 131072);
    (void)hipFuncSetAttribute((const void*)k_gemm256<1>,
                              hipFuncAttributeMaxDynamicSharedMemorySize, 131072);

    // fused preprocessing + merged W1/W2 transpose (r14-verified)
    {
        const int NX = B_SZ * (IN_DD / 8);
        const int NO = B_SZ * 128 / 4;
        const int NW3 = NAGENT * NA_N * H2_D;
        int n = NX + NO + NW3;
        k_prep<<<(n + 255) / 256, 256, 0, stream>>>(obs, act, Xb, b3, out, W3, W3T);
    }
    k_transpose_w12<<<dim3(IN_DD / 32, 1024 / 32, 16), dim3(32, 8), 0, stream>>>(
        W1, W1T, W2, W2T);

    const size_t agElems = (size_t)B_SZ * H1_D;
    bf16* h1 = (bf16*)hbase;

    for (int g0 = 0; g0 < NAGENT; g0 += G) {
        k_gemm256<0><<<dim3(GRID_M, GRID_N, G), 512, 131072, stream>>>(
            Xb, 0, IN_DD, W1T, b1, h1, agElems, IN_DD, g0, G, nullptr, nullptr);
        k_gemm256<1><<<dim3(GRID_M, GRID_N, G), 512, 131072, stream>>>(
            h1, agElems, H1_D, W2T, b2, nullptr, 0, H1_D, g0, G, W3T, out);
    }
    (void)in_sizes; (void)n_in; (void)out_size;
}